// Round 8
// baseline (173.900 us; speedup 1.0000x reference)
//
#include <hip/hip_runtime.h>

// Network24 — ROUND 8: MEASUREMENT ROUND.
// R3-R7 all plateau at ~40 us kernel time with no saturated pipe (VALU<=34%,
// HBM<=20%, occ 68%). All models predict <=20 us. Two probes isolate the cause:
//   Probe A: hipMemcpyAsync d2d 64 MiB (SDK streaming reference).
//   Probe B: copy kernel with EXACTLY net24's wave shape (one-shot wave per
//            256-row tile, 2x dwordx4 load + 2x dwordx4 store), 2x-x-sized
//            (256 MB traffic) so it lands in the rocprof top-5 either way.
// Control: R5's kernel verbatim (best dur_us so far).

typedef float vfloat4 __attribute__((ext_vector_type(4)));
typedef float vfloat2 __attribute__((ext_vector_type(2)));

__device__ __forceinline__ float sigmoid_fast(float z) {
    float t = __expf(-z);
    return __builtin_amdgcn_rcpf(1.0f + t);
}
__device__ __forceinline__ float sigmoid_exact(float z) {
    return 1.0f / (1.0f + expf(-z));
}
__device__ __forceinline__ float pw(float x, float p) {
    return (p == 1.0f) ? x : __powf(x, p);
}

// ---- Probe B: net24-shaped pure copy (no math) ----
__global__ __launch_bounds__(256) void probe_copy(const vfloat4* __restrict__ src,
                                                  vfloat4* __restrict__ dst,
                                                  long long src_tiles,
                                                  long long total_tiles) {
    const long long gid = (long long)blockIdx.x * blockDim.x + threadIdx.x;
    const long long w   = gid >> 6;         // one wave per tile, one-shot
    const int lane      = (int)(gid & 63);
    if (w >= total_tiles) return;
    const vfloat4* s = src + (w % src_tiles) * 128;   // 128 float4 = 2 KB tile
    vfloat4* d       = dst + w * 128;
    vfloat4 a = s[lane];
    vfloat4 b = s[64 + lane];
    d[lane]      = a;
    d[64 + lane] = b;
}

// ---- Control: R5 kernel verbatim ----
__global__ __launch_bounds__(256) void net24_kernel(
    const float* __restrict__ x,
    float* __restrict__ out,
    const float* __restrict__ fc1_tw,
    const float* __restrict__ fc1_power,
    const float* __restrict__ fc1_bias,
    const float* __restrict__ m4_tw,
    const float* __restrict__ m4_power,
    const float* __restrict__ m4_bias3,
    int n)
{
    const float tw00 = fc1_tw[0], tw01 = fc1_tw[3], tw10 = fc1_tw[6], tw11 = fc1_tw[9];
    const float p00 = fc1_power[0], p01 = fc1_power[1], p10 = fc1_power[2], p11 = fc1_power[3];
    const float b0 = fc1_bias[0], b1 = fc1_bias[1];
    const float m0 = m4_tw[0], m1 = m4_tw[3], m2 = m4_tw[6], m3 = m4_tw[9];
    const float q0 = m4_power[0], q1 = m4_power[1], q2 = m4_power[2], q3 = m4_power[3];
    const float bias3 = m4_bias3[0];

    const bool all_pow1 = (p00 == 1.0f) & (p01 == 1.0f) & (p10 == 1.0f) & (p11 == 1.0f) &
                          (q0 == 1.0f) & (q1 == 1.0f) & (q2 == 1.0f) & (q3 == 1.0f);

    auto eval_fast = [&](float x0, float x1) -> float {
        float h0 = sigmoid_fast(fmaf(tw00, x0, fmaf(tw01, x1, b0)));
        float h1 = sigmoid_fast(fmaf(tw10, x0, fmaf(tw11, x1, b1)));
        float s  = fmaf(m0, h0, fmaf(m1, h1, bias3));
        s = fmaf(m2 * h0, m3 * h1, s);
        return sigmoid_fast(s);
    };
    auto eval_gen = [&](float x0, float x1) -> float {
        float h0 = sigmoid_exact(fmaf(tw00, pw(x0, p00), fmaf(tw01, pw(x1, p01), b0)));
        float h1 = sigmoid_exact(fmaf(tw10, pw(x0, p10), fmaf(tw11, pw(x1, p11), b1)));
        float s  = fmaf(m0, pw(h0, q0), fmaf(m1, pw(h1, q1), bias3));
        s = fmaf(m2 * pw(h0, q2), m3 * pw(h1, q3), s);
        return sigmoid_exact(s);
    };

    const int gid  = blockIdx.x * blockDim.x + threadIdx.x;
    const int wave = gid >> 6;
    const int lane = gid & 63;
    const long long rowbase = (long long)wave * 256;
    if (rowbase >= n) return;

    if (all_pow1 && rowbase + 256 <= n) {
        const vfloat4* xv = (const vfloat4*)(x + rowbase * 2);
        vfloat4 a = xv[lane];
        vfloat4 b = xv[64 + lane];
        vfloat2 ra, rb;
        ra.x = eval_fast(a.x, a.y);
        ra.y = eval_fast(a.z, a.w);
        rb.x = eval_fast(b.x, b.y);
        rb.y = eval_fast(b.z, b.w);
        *(vfloat2*)(out + rowbase + 2 * lane)       = ra;
        *(vfloat2*)(out + rowbase + 128 + 2 * lane) = rb;
    } else {
        for (long long r = rowbase + lane; r < rowbase + 256 && r < n; r += 64) {
            out[r] = eval_gen(x[r * 2], x[r * 2 + 1]);
        }
    }
}

extern "C" void kernel_launch(void* const* d_in, const int* in_sizes, int n_in,
                              void* d_out, int out_size, void* d_ws, size_t ws_size,
                              hipStream_t stream) {
    const float* x         = (const float*)d_in[0];
    const float* fc1_tw    = (const float*)d_in[1];
    const float* fc1_power = (const float*)d_in[2];
    const float* fc1_bias  = (const float*)d_in[3];
    const float* m4_tw     = (const float*)d_in[4];
    const float* m4_power  = (const float*)d_in[5];
    const float* m4_bias3  = (const float*)d_in[6];
    float* out = (float*)d_out;

    const int n = out_size;                               // 8388608 rows
    const long long ntiles = ((long long)n + 255) / 256;  // 32768 tiles
    const size_t x_bytes = (size_t)n * 2 * sizeof(float); // 64 MiB

    // ---- Diagnostic probes (run every call; same work each call) ----
    if (ws_size >= x_bytes + (size_t)2 * ntiles * 2048) {
        // Probe A: SDK streaming d2d copy, 64 MiB.
        hipMemcpyAsync(d_ws, (const void*)x, x_bytes, hipMemcpyDeviceToDevice, stream);
        // Probe B: net24-shaped copy, 2 passes over x (128 MB read + 128 MB write).
        const long long total_tiles = 2 * ntiles;                 // 65536 waves
        const long long blocks = (total_tiles * 64 + 255) / 256;  // 16384 blocks
        vfloat4* dstB = (vfloat4*)((char*)d_ws + x_bytes);
        probe_copy<<<(int)blocks, 256, 0, stream>>>((const vfloat4*)x, dstB,
                                                    ntiles, total_tiles);
    }

    // ---- Real kernel (R5 structure, unchanged) ----
    const long long waves = ntiles;
    const long long threads = waves * 64;
    const long long grid = (threads + 255) / 256;
    net24_kernel<<<(int)grid, 256, 0, stream>>>(x, out, fc1_tw, fc1_power, fc1_bias,
                                                m4_tw, m4_power, m4_bias3, n);
}

// Round 9
// 109.302 us; speedup vs baseline: 1.5910x; 1.5910x over previous
//
#include <hip/hip_runtime.h>

// Network24: out = sigmoid( m0*h0 + m1*h1 + (m2*h0)*(m3*h1) + bias3 )
//   h_j = sigmoid( tw[j][0]*x0 + tw[j][1]*x1 + b_j )        (powers == 1.0)
//
// R8 probes: net24-shaped mathless copy hits >=6.2 TB/s -> structure/memory
// exonerated. Waves stall ~94% of residency only when math present -> theory:
// insufficient independent chains per wave (4 rows/lane). R9: 512-row
// wave-tiles = 8 rows/lane, 4 back-to-back coalesced float4 loads (2x MLP),
// 24 independent sigmoid chains/lane (2x ILP), half the waves. Weights
// pre-negated (scalar side) so each sigmoid is exp->add->rcp with no negate.

typedef float vfloat4 __attribute__((ext_vector_type(4)));
typedef float vfloat2 __attribute__((ext_vector_type(2)));

__device__ __forceinline__ float sigmoid_exact(float z) {
    return 1.0f / (1.0f + expf(-z));
}
__device__ __forceinline__ float pw(float x, float p) {
    return (p == 1.0f) ? x : __powf(x, p);
}

__global__ __launch_bounds__(256) void net24_kernel(
    const float* __restrict__ x,        // (n, 2) row-major
    float* __restrict__ out,            // (n,)
    const float* __restrict__ fc1_tw,   // (2,2,3) -> [j,k,0] = j*6+k*3
    const float* __restrict__ fc1_power,// (2,2)
    const float* __restrict__ fc1_bias, // (2,)
    const float* __restrict__ m4_tw,    // (4,3) -> [i,0] = i*3
    const float* __restrict__ m4_power, // (4,)
    const float* __restrict__ m4_bias3, // (1,)
    int n)
{
    const float tw00 = fc1_tw[0], tw01 = fc1_tw[3], tw10 = fc1_tw[6], tw11 = fc1_tw[9];
    const float p00 = fc1_power[0], p01 = fc1_power[1], p10 = fc1_power[2], p11 = fc1_power[3];
    const float b0 = fc1_bias[0], b1 = fc1_bias[1];
    const float m0 = m4_tw[0], m1 = m4_tw[3], m2 = m4_tw[6], m3 = m4_tw[9];
    const float q0 = m4_power[0], q1 = m4_power[1], q2 = m4_power[2], q3 = m4_power[3];
    const float bias3 = m4_bias3[0];

    const bool all_pow1 = (p00 == 1.0f) & (p01 == 1.0f) & (p10 == 1.0f) & (p11 == 1.0f) &
                          (q0 == 1.0f) & (q1 == 1.0f) & (q2 == 1.0f) & (q3 == 1.0f);

    // Pre-negated scalar constants: sigmoid(z) = rcp(1 + exp(-z)); we build
    // -z directly so each sigmoid is exp, add, rcp (no per-lane negation).
    const float ntw00 = -tw00, ntw01 = -tw01, nb0 = -b0;
    const float ntw10 = -tw10, ntw11 = -tw11, nb1 = -b1;
    const float nm0 = -m0, nm1 = -m1, nM = -(m2 * m3), nbias3 = -bias3;

    auto eval_fast = [&](float x0, float x1) -> float {
        float zn0 = fmaf(ntw00, x0, fmaf(ntw01, x1, nb0));
        float zn1 = fmaf(ntw10, x0, fmaf(ntw11, x1, nb1));
        float h0 = __builtin_amdgcn_rcpf(1.0f + __expf(zn0));
        float h1 = __builtin_amdgcn_rcpf(1.0f + __expf(zn1));
        float sn = fmaf(nM * h0, h1, fmaf(nm0, h0, fmaf(nm1, h1, nbias3)));
        return __builtin_amdgcn_rcpf(1.0f + __expf(sn));
    };
    auto eval_gen = [&](float x0, float x1) -> float {
        float h0 = sigmoid_exact(fmaf(tw00, pw(x0, p00), fmaf(tw01, pw(x1, p01), b0)));
        float h1 = sigmoid_exact(fmaf(tw10, pw(x0, p10), fmaf(tw11, pw(x1, p11), b1)));
        float s  = fmaf(m0, pw(h0, q0), fmaf(m1, pw(h1, q1), bias3));
        s = fmaf(m2 * pw(h0, q2), m3 * pw(h1, q3), s);
        return sigmoid_exact(s);
    };

    const int gid  = blockIdx.x * blockDim.x + threadIdx.x;
    const int wave = gid >> 6;
    const int lane = gid & 63;
    const long long rowbase = (long long)wave * 512;   // 512-row wave-tile
    if (rowbase >= n) return;

    if (all_pow1 && rowbase + 512 <= n) {
        // 4 coalesced float4 loads, issued back-to-back (4 KB/wave in flight).
        // Chunk k, lane l holds rows rowbase + 128k + 2l, +2l+1.
        const vfloat4* xv = (const vfloat4*)(x + rowbase * 2);  // 256 float4s
        vfloat4 c0 = xv[lane];
        vfloat4 c1 = xv[64 + lane];
        vfloat4 c2 = xv[128 + lane];
        vfloat4 c3 = xv[192 + lane];

        // 8 independent rows per lane -> 24 interleavable sigmoid chains.
        vfloat2 r0, r1, r2, r3;
        r0.x = eval_fast(c0.x, c0.y);  r0.y = eval_fast(c0.z, c0.w);
        r1.x = eval_fast(c1.x, c1.y);  r1.y = eval_fast(c1.z, c1.w);
        r2.x = eval_fast(c2.x, c2.y);  r2.y = eval_fast(c2.z, c2.w);
        r3.x = eval_fast(c3.x, c3.y);  r3.y = eval_fast(c3.z, c3.w);

        float* o = out + rowbase;
        *(vfloat2*)(o +       2 * lane) = r0;   // each instr: 512 B contiguous
        *(vfloat2*)(o + 128 + 2 * lane) = r1;
        *(vfloat2*)(o + 256 + 2 * lane) = r2;
        *(vfloat2*)(o + 384 + 2 * lane) = r3;
    } else {
        // Generic / tail path.
        for (long long r = rowbase + lane; r < rowbase + 512 && r < n; r += 64) {
            out[r] = eval_gen(x[r * 2], x[r * 2 + 1]);
        }
    }
}

extern "C" void kernel_launch(void* const* d_in, const int* in_sizes, int n_in,
                              void* d_out, int out_size, void* d_ws, size_t ws_size,
                              hipStream_t stream) {
    const float* x         = (const float*)d_in[0];
    const float* fc1_tw    = (const float*)d_in[1];
    const float* fc1_power = (const float*)d_in[2];
    const float* fc1_bias  = (const float*)d_in[3];
    const float* m4_tw     = (const float*)d_in[4];
    const float* m4_power  = (const float*)d_in[5];
    const float* m4_bias3  = (const float*)d_in[6];
    float* out = (float*)d_out;

    const int n = out_size;                               // 8388608 rows
    const long long ntiles = ((long long)n + 511) / 512;  // 16384 wave-tiles
    const long long threads = ntiles * 64;
    const long long grid = (threads + 255) / 256;         // 4096 blocks

    net24_kernel<<<(int)grid, 256, 0, stream>>>(x, out, fc1_tw, fc1_power, fc1_bias,
                                                m4_tw, m4_power, m4_bias3, n);
}

// Round 10
// 107.542 us; speedup vs baseline: 1.6170x; 1.0164x over previous
//
#include <hip/hip_runtime.h>

// Network24: out = sigmoid( m0*h0 + m1*h1 + (m2*h0)*(m3*h1) + bias3 )
//   h_j = sigmoid( tw[j][0]*x0 + tw[j][1]*x1 + b_j )        (powers == 1.0)
//
// R9 post-mortem: ILP/MLP/persistence/coalescing/VALU-count ALL neutral.
// Invariant: every slow kernel (38-46us) contains trans-pipe ops
// (v_exp_f32/v_rcp_f32); probe B (same wave shape, zero trans) runs at
// >=6.2 TB/s. R10 hypothesis test: fully TRANS-FREE sigmoid.
//   exp(t): n=rndne(t*log2e), f=t*log2e-n, 2^f deg-5 Taylor (rel 2.4e-6),
//           scale v_ldexp_f32.
//   1/u:    bit-trick init 0x7EF311C3 + 2 Newton steps (rel ~6e-6).
// All full-rate VALU. If trans was the curse -> kernel ~15-20us. If neutral,
// trans exonerated (decisive either way).

typedef float vfloat4 __attribute__((ext_vector_type(4)));
typedef float vfloat2 __attribute__((ext_vector_type(2)));

__device__ __forceinline__ float sigmoid_exact(float z) {
    return 1.0f / (1.0f + expf(-z));
}
__device__ __forceinline__ float pw(float x, float p) {
    return (p == 1.0f) ? x : __powf(x, p);
}

// sigma(z) with zn = -z as input: 1/(1+exp(zn)). Zero trans-pipe ops.
__device__ __forceinline__ float sigmoid_notrans(float zn) {
    const float LOG2E = 1.4426950408889634f;
    float t = zn * LOG2E;
    t = fminf(fmaxf(t, -126.0f), 126.0f);          // keep ldexp in range
    float nf = __builtin_rintf(t);                 // v_rndne_f32
    float f  = t - nf;                             // f in [-0.5, 0.5]
    // 2^f, Taylor deg 5 about 0: max rel err 2.4e-6 on [-0.5,0.5]
    float p = fmaf(f, 1.3333558146428443e-3f, 9.6181290919849850e-3f);
    p = fmaf(f, p, 5.5504108664821580e-2f);
    p = fmaf(f, p, 2.4022650695910072e-1f);
    p = fmaf(f, p, 6.9314718055994531e-1f);
    p = fmaf(f, p, 1.0f);
    float e = ldexpf(p, (int)nf);                  // v_ldexp_f32
    float u = 1.0f + e;
    // 1/u: bit-trick init (~3% err) + 2 Newton steps -> ~1e-6 rel
    float y = __int_as_float(0x7EF311C3 - __float_as_int(u));
    y = y * fmaf(-u, y, 2.0f);
    y = y * fmaf(-u, y, 2.0f);
    return y;
}

__global__ __launch_bounds__(256) void net24_kernel(
    const float* __restrict__ x,        // (n, 2) row-major
    float* __restrict__ out,            // (n,)
    const float* __restrict__ fc1_tw,   // (2,2,3) -> [j,k,0] = j*6+k*3
    const float* __restrict__ fc1_power,// (2,2)
    const float* __restrict__ fc1_bias, // (2,)
    const float* __restrict__ m4_tw,    // (4,3) -> [i,0] = i*3
    const float* __restrict__ m4_power, // (4,)
    const float* __restrict__ m4_bias3, // (1,)
    int n)
{
    const float tw00 = fc1_tw[0], tw01 = fc1_tw[3], tw10 = fc1_tw[6], tw11 = fc1_tw[9];
    const float p00 = fc1_power[0], p01 = fc1_power[1], p10 = fc1_power[2], p11 = fc1_power[3];
    const float b0 = fc1_bias[0], b1 = fc1_bias[1];
    const float m0 = m4_tw[0], m1 = m4_tw[3], m2 = m4_tw[6], m3 = m4_tw[9];
    const float q0 = m4_power[0], q1 = m4_power[1], q2 = m4_power[2], q3 = m4_power[3];
    const float bias3 = m4_bias3[0];

    const bool all_pow1 = (p00 == 1.0f) & (p01 == 1.0f) & (p10 == 1.0f) & (p11 == 1.0f) &
                          (q0 == 1.0f) & (q1 == 1.0f) & (q2 == 1.0f) & (q3 == 1.0f);

    // Pre-negated constants so each sigmoid consumes -z directly.
    const float ntw00 = -tw00, ntw01 = -tw01, nb0 = -b0;
    const float ntw10 = -tw10, ntw11 = -tw11, nb1 = -b1;
    const float nm0 = -m0, nm1 = -m1, nM = -(m2 * m3), nbias3 = -bias3;

    auto eval_fast = [&](float x0, float x1) -> float {
        float zn0 = fmaf(ntw00, x0, fmaf(ntw01, x1, nb0));
        float zn1 = fmaf(ntw10, x0, fmaf(ntw11, x1, nb1));
        float h0 = sigmoid_notrans(zn0);
        float h1 = sigmoid_notrans(zn1);
        float sn = fmaf(nM * h0, h1, fmaf(nm0, h0, fmaf(nm1, h1, nbias3)));
        return sigmoid_notrans(sn);
    };
    auto eval_gen = [&](float x0, float x1) -> float {
        float h0 = sigmoid_exact(fmaf(tw00, pw(x0, p00), fmaf(tw01, pw(x1, p01), b0)));
        float h1 = sigmoid_exact(fmaf(tw10, pw(x0, p10), fmaf(tw11, pw(x1, p11), b1)));
        float s  = fmaf(m0, pw(h0, q0), fmaf(m1, pw(h1, q1), bias3));
        s = fmaf(m2 * pw(h0, q2), m3 * pw(h1, q3), s);
        return sigmoid_exact(s);
    };

    const int gid  = blockIdx.x * blockDim.x + threadIdx.x;
    const int wave = gid >> 6;
    const int lane = gid & 63;
    const long long rowbase = (long long)wave * 256;   // 256-row wave-tile
    if (rowbase >= n) return;

    if (all_pow1 && rowbase + 256 <= n) {
        // Verified-best access shape (R5): unit-stride float4 loads,
        // each lane's float4 = 2 complete rows, vfloat2 unit-stride stores.
        const vfloat4* xv = (const vfloat4*)(x + rowbase * 2);
        vfloat4 a = xv[lane];
        vfloat4 b = xv[64 + lane];
        vfloat2 ra, rb;
        ra.x = eval_fast(a.x, a.y);
        ra.y = eval_fast(a.z, a.w);
        rb.x = eval_fast(b.x, b.y);
        rb.y = eval_fast(b.z, b.w);
        *(vfloat2*)(out + rowbase + 2 * lane)       = ra;
        *(vfloat2*)(out + rowbase + 128 + 2 * lane) = rb;
    } else {
        for (long long r = rowbase + lane; r < rowbase + 256 && r < n; r += 64) {
            out[r] = eval_gen(x[r * 2], x[r * 2 + 1]);
        }
    }
}

extern "C" void kernel_launch(void* const* d_in, const int* in_sizes, int n_in,
                              void* d_out, int out_size, void* d_ws, size_t ws_size,
                              hipStream_t stream) {
    const float* x         = (const float*)d_in[0];
    const float* fc1_tw    = (const float*)d_in[1];
    const float* fc1_power = (const float*)d_in[2];
    const float* fc1_bias  = (const float*)d_in[3];
    const float* m4_tw     = (const float*)d_in[4];
    const float* m4_power  = (const float*)d_in[5];
    const float* m4_bias3  = (const float*)d_in[6];
    float* out = (float*)d_out;

    const int n = out_size;                               // 8388608 rows
    const long long waves = ((long long)n + 255) / 256;   // 32768 wave-tiles
    const long long threads = waves * 64;
    const long long grid = (threads + 255) / 256;         // 8192 blocks

    net24_kernel<<<(int)grid, 256, 0, stream>>>(x, out, fc1_tw, fc1_power, fc1_bias,
                                                m4_tw, m4_power, m4_bias3, n);
}